// Round 9
// baseline (170.648 us; speedup 1.0000x reference)
//
#include <hip/hip_runtime.h>

#define BB 8
#define SS 4096
#define DD 256
#define NEGV -1000000000.0f
#define NCH (SS / 32)   // 128 s-chunks of 32
#define SPLIT 16

typedef float f32x4 __attribute__((ext_vector_type(4)));
typedef short s16x8 __attribute__((ext_vector_type(8)));

// float -> bf16 round-to-nearest-even (inputs finite)
static __device__ __forceinline__ unsigned short f2bf(float x) {
  unsigned int u = __builtin_bit_cast(unsigned int, x);
  u += 0x7fffu + ((u >> 16) & 1u);
  return (unsigned short)(u >> 16);
}
static __device__ __forceinline__ float bf2f(unsigned short h) {
  return __builtin_bit_cast(float, (unsigned int)h << 16);
}

// async global->LDS, 16B per lane; LDS dest = wave-uniform base + lane*16
static __device__ __forceinline__ void gload_lds16(
    const unsigned short* __restrict__ g, unsigned short* l) {
  __builtin_amdgcn_global_load_lds(
      (const __attribute__((address_space(1))) void*)g,
      (__attribute__((address_space(3))) void*)l, 16, 0, 0);
}

// ---------------------------------------------------------------------------
// prep: K/V only (Q folded into p3 -- its norm factors out). grid (S/32,B,2):
// z=0 -> KT (scaled 1/|k|^2), z=1 -> VT. Chunked transpose
// dst[((b*NCH+sc)*D + d)*32 + s'] = bf16(src*scl). R7-verified, at its
// measured pattern ceiling (~3.35 TB/s aggregate across 3 structures).
// ---------------------------------------------------------------------------
__global__ __launch_bounds__(256, 4) void prep_kernel(
    const float* __restrict__ K, const float* __restrict__ V,
    unsigned short* __restrict__ KT, unsigned short* __restrict__ VT) {
  __shared__ unsigned short tile[32 * 260];
  const int b = blockIdx.y;
  const int sc = blockIdx.x;
  const int s0 = sc * 32;
  const int tid = threadIdx.x;
  const int w = tid >> 6, l = tid & 63;
  const int isK = (blockIdx.z == 0);
  const float* __restrict__ src = isK ? K : V;
  unsigned short* __restrict__ dst = isK ? KT : VT;

  float4 reg[8];
  float ps[8];
#pragma unroll
  for (int it = 0; it < 8; ++it) {
    const int row = it * 4 + w;
    reg[it] = *(const float4*)(src + ((size_t)b * SS + s0 + row) * DD + l * 4);
  }
#pragma unroll
  for (int it = 0; it < 8; ++it)
    ps[it] = reg[it].x * reg[it].x + reg[it].y * reg[it].y +
             reg[it].z * reg[it].z + reg[it].w * reg[it].w;
  float scl[8];
  if (isK) {
#pragma unroll
    for (int off = 32; off; off >>= 1)
#pragma unroll
      for (int it = 0; it < 8; ++it) ps[it] += __shfl_xor(ps[it], off);
#pragma unroll
    for (int it = 0; it < 8; ++it) scl[it] = 1.0f / ps[it];
  } else {
#pragma unroll
    for (int it = 0; it < 8; ++it) scl[it] = 1.0f;
  }
#pragma unroll
  for (int it = 0; it < 8; ++it) {
    const int row = it * 4 + w;
    ushort4 o;
    o.x = f2bf(reg[it].x * scl[it]);
    o.y = f2bf(reg[it].y * scl[it]);
    o.z = f2bf(reg[it].z * scl[it]);
    o.w = f2bf(reg[it].w * scl[it]);
    *(ushort4*)(tile + row * 260 + l * 4) = o;
  }
  __syncthreads();
  const size_t gbase = ((size_t)(b * NCH + sc) * DD + tid) * 32;
#pragma unroll
  for (int c = 0; c < 4; ++c) {
    union { unsigned short h[8]; uint4 v; } u;
#pragma unroll
    for (int j = 0; j < 8; ++j) u.h[j] = tile[(c * 8 + j) * 260 + tid];
    *(uint4*)(dst + gbase + c * 8) = u.v;
  }
}

// ---------------------------------------------------------------------------
// p2: part[y][b][e][d] (bf16) = sum_{s in chunk y} VT[e][s]*KT[d][s].
// R7-verified single-phase body, bf16 partials.
// ---------------------------------------------------------------------------
__global__ __launch_bounds__(256) void p2_kernel(
    const unsigned short* __restrict__ KT, const unsigned short* __restrict__ VT,
    unsigned short* __restrict__ part, int iters) {
  __shared__ unsigned short vt_l[2][128 * 32];
  __shared__ unsigned short kt_l[2][128 * 32];
  const int b = blockIdx.z;
  const int d0 = (blockIdx.x & 1) * 128;
  const int e0 = (blockIdx.x >> 1) * 128;
  const int tid = threadIdx.x;
  const int w = tid >> 6, l = tid & 63;
  const int wr = w & 1, wc = w >> 1;
  const int quad = l >> 4, mr = l & 15;

  f32x4 acc[4][4];
#pragma unroll
  for (int i = 0; i < 4; ++i)
#pragma unroll
    for (int j = 0; j < 4; ++j) acc[i][j] = (f32x4){0.f, 0.f, 0.f, 0.f};

  for (int ks = 0; ks < iters; ++ks) {
    const int c0 = (blockIdx.y * iters + ks) * 2;  // 32-wide chunk index
#pragma unroll
    for (int h = 0; h < 2; ++h) {
      const size_t vch = ((size_t)(b * NCH + c0 + h) * DD + e0) * 32 + l * 8;
      const size_t kch = ((size_t)(b * NCH + c0 + h) * DD + d0) * 32 + l * 8;
#pragma unroll
      for (int g = 0; g < 2; ++g) {
        const int r0 = w * 32 + g * 16;
        gload_lds16(VT + vch + (size_t)r0 * 32, &vt_l[h][r0 * 32]);
        gload_lds16(KT + kch + (size_t)r0 * 32, &kt_l[h][r0 * 32]);
      }
    }
    __syncthreads();
#pragma unroll
    for (int kh = 0; kh < 2; ++kh) {
      s16x8 af[4], bfr[4];
#pragma unroll
      for (int i = 0; i < 4; ++i)
        af[i] = *(const s16x8*)(&vt_l[kh][(wr * 64 + i * 16 + mr) * 32 + quad * 8]);
#pragma unroll
      for (int j = 0; j < 4; ++j)
        bfr[j] = *(const s16x8*)(&kt_l[kh][(wc * 64 + j * 16 + mr) * 32 + quad * 8]);
#pragma unroll
      for (int i = 0; i < 4; ++i)
#pragma unroll
        for (int j = 0; j < 4; ++j)
          acc[i][j] = __builtin_amdgcn_mfma_f32_16x16x32_bf16(af[i], bfr[j],
                                                              acc[i][j], 0, 0, 0);
    }
    __syncthreads();
  }

  unsigned short* pb = part + ((size_t)blockIdx.y * BB + b) * DD * DD;
#pragma unroll
  for (int i = 0; i < 4; ++i) {
    const int e = e0 + wr * 64 + i * 16 + quad * 4;
#pragma unroll
    for (int j = 0; j < 4; ++j) {
      const int d = d0 + wc * 64 + j * 16 + mr;
      unsigned short* p = pb + (size_t)e * DD + d;
#pragma unroll
      for (int r = 0; r < 4; ++r) p[(size_t)r * DD] = f2bf(acc[i][j][r]);
    }
  }
}

// ---------------------------------------------------------------------------
// reduce: s1b[b][e][d] = bf16(sum_p part[p][b][e][d]); colsum[b][e] = f32
// sum over d (p3's masked-row path). Shuffle reduce, no atomics. R7-verified.
// ---------------------------------------------------------------------------
__global__ __launch_bounds__(256) void reduce_kernel(
    const unsigned short* __restrict__ part, unsigned short* __restrict__ s1b,
    float* __restrict__ colsum) {
  const int tid = threadIdx.x;
  const size_t i8 = ((size_t)blockIdx.x * 256 + tid) * 8;
  float a[8];
#pragma unroll
  for (int j = 0; j < 8; ++j) a[j] = 0.f;
  for (int p = 0; p < SPLIT; ++p) {
    union { uint4 v; unsigned short h[8]; } u;
    u.v = *(const uint4*)(part + (size_t)p * (BB * DD * DD) + i8);
#pragma unroll
    for (int j = 0; j < 8; ++j) a[j] += bf2f(u.h[j]);
  }
  union { uint4 v; unsigned short h[8]; } o;
#pragma unroll
  for (int j = 0; j < 8; ++j) o.h[j] = f2bf(a[j]);
  *(uint4*)(s1b + i8) = o.v;
  float rp = (a[0] + a[1]) + (a[2] + a[3]) + ((a[4] + a[5]) + (a[6] + a[7]));
  rp += __shfl_xor(rp, 1);
  rp += __shfl_xor(rp, 2);
  rp += __shfl_xor(rp, 4);
  rp += __shfl_xor(rp, 8);
  rp += __shfl_xor(rp, 16);
  if ((tid & 31) == 0) {
    const int e = (int)((i8 >> 8) & 255);
    const int bb = (int)(i8 >> 16);
    colsum[bb * DD + e] = rp;
  }
}

// ---------------------------------------------------------------------------
// p3: out[b][s][e] = (1/D)*( mask[s] ? NEG*colsum[e]
//                                    : (1/|Q_s|^2) * sum_d Q[s][d]*s1b[e][d] )
// R9: T14 async-stage split + ks double-buffer. Per iteration: issue next
// step's s1-DMA + Q-register-loads FIRST, run the 32-MFMA cluster on the
// current buffer, THEN consume the Q regs (norm+cvt+ds_write) -- the vmcnt
// wait for the register loads lands after the MFMAs, hiding ~500-900cy HBM
// latency that R7 exposed serially 4x per block. LDS 66KB -> 2 blocks/CU
// (grid is 512 = 2/CU anyway).
// ---------------------------------------------------------------------------
__global__ __launch_bounds__(256) void p3_kernel(
    const float* __restrict__ Q, const int* __restrict__ mask,
    const unsigned short* __restrict__ s1b, const float* __restrict__ colsum,
    float* __restrict__ out) {
  // [ksbuf][kh][...]; qs keeps the +16-short pad between kh halves.
  __shared__ unsigned short qs_l[2][2][128 * 32 + 16];
  __shared__ unsigned short s1_l[2][2][128 * 32];
  __shared__ float ps_l[128];
  __shared__ float ca_l[128];
  __shared__ float cs_l[128];
  const int b = blockIdx.z;
  const int e0 = blockIdx.x * 128;
  const int s0 = blockIdx.y * 128;
  const int tid = threadIdx.x;
  const int w = tid >> 6, l = tid & 63;
  const int wr = w & 1, wc = w >> 1;
  const int quad = l >> 4, mr = l & 15;
  const int lr = l >> 2;
  const int lc = (l & 3) * 8;
  const int rg = tid >> 4;   // row group: rows rg, rg+16, ..., rg+112
  const int c4 = tid & 15;   // float4 column within the 64-d k-step

  if (tid < 128) cs_l[tid] = colsum[b * DD + e0 + tid];

  f32x4 acc[4][4];
#pragma unroll
  for (int i = 0; i < 4; ++i)
#pragma unroll
    for (int j = 0; j < 4; ++j) acc[i][j] = (f32x4){0.f, 0.f, 0.f, 0.f};
  float np[8];
#pragma unroll
  for (int u = 0; u < 8; ++u) np[u] = 0.f;

  auto stageS1 = [&](int buf, int ks) {
    const int dc = ks * 64;
#pragma unroll
    for (int h = 0; h < 2; ++h)
#pragma unroll
      for (int g = 0; g < 2; ++g) {
        const int r0 = w * 32 + g * 16;
        gload_lds16(s1b + ((size_t)b * DD + e0 + r0 + lr) * DD + dc + h * 32 + lc,
                    &s1_l[buf][h][r0 * 32]);
      }
  };
  auto loadQ = [&](int ks, float4* qv) {
    const int dc = ks * 64;
#pragma unroll
    for (int u = 0; u < 8; ++u) {
      const int row = rg + u * 16;
      qv[u] = *(const float4*)(Q + ((size_t)b * SS + s0 + row) * DD + dc + c4 * 4);
    }
  };
  auto writeQ = [&](int buf, const float4* qv) {
#pragma unroll
    for (int u = 0; u < 8; ++u) {
      np[u] += qv[u].x * qv[u].x + qv[u].y * qv[u].y + qv[u].z * qv[u].z +
               qv[u].w * qv[u].w;
      ushort4 o;
      o.x = f2bf(qv[u].x); o.y = f2bf(qv[u].y);
      o.z = f2bf(qv[u].z); o.w = f2bf(qv[u].w);
      *(ushort4*)&qs_l[buf][c4 >> 3][(rg + u * 16) * 32 + (c4 & 7) * 4] = o;
    }
  };

  // prologue: stage ks=0 (latency exposed once)
  float4 qvA[8], qvB[8];
  stageS1(0, 0);
  loadQ(0, qvA);
  writeQ(0, qvA);
  __syncthreads();

  for (int ks = 0; ks < 4; ++ks) {
    const int cur = ks & 1;
    if (ks < 3) {
      stageS1(cur ^ 1, ks + 1);  // DMA: latency hidden under MFMAs
      loadQ(ks + 1, qvB);        // reg loads: vmcnt wait lands in writeQ below
    }
#pragma unroll
    for (int kh = 0; kh < 2; ++kh) {
      s16x8 af[4], bfr[4];
#pragma unroll
      for (int i = 0; i < 4; ++i)
        af[i] = *(const s16x8*)(&qs_l[cur][kh][(wr * 64 + i * 16 + mr) * 32 + quad * 8]);
#pragma unroll
      for (int j = 0; j < 4; ++j)
        bfr[j] = *(const s16x8*)(&s1_l[cur][kh][(wc * 64 + j * 16 + mr) * 32 + quad * 8]);
#pragma unroll
      for (int i = 0; i < 4; ++i)
#pragma unroll
        for (int j = 0; j < 4; ++j)
          acc[i][j] = __builtin_amdgcn_mfma_f32_16x16x32_bf16(af[i], bfr[j],
                                                              acc[i][j], 0, 0, 0);
    }
    if (ks < 3) writeQ(cur ^ 1, qvB);  // consume Q regs after MFMA cluster
    __syncthreads();
  }

  // finalize row norms: reduce over the 16-thread group (c4 axis)
#pragma unroll
  for (int u = 0; u < 8; ++u) {
    np[u] += __shfl_xor(np[u], 1);
    np[u] += __shfl_xor(np[u], 2);
    np[u] += __shfl_xor(np[u], 4);
    np[u] += __shfl_xor(np[u], 8);
  }
  if (c4 == 0) {
#pragma unroll
    for (int u = 0; u < 8; ++u) ps_l[rg + u * 16] = np[u];
  }
  __syncthreads();
  if (tid < 128) {
    const int mk = mask[b * SS + s0 + tid];
    ca_l[tid] = mk ? 0.0f : (1.0f / ps_l[tid]);  // 0 == masked sentinel
  }
  __syncthreads();

#pragma unroll
  for (int i = 0; i < 4; ++i) {
#pragma unroll
    for (int j = 0; j < 4; ++j) {
      const int el = wc * 64 + j * 16 + mr;
      const float csum = cs_l[el];
      float* p = out + ((size_t)b * SS + s0 + wr * 64 + i * 16 + quad * 4) * DD +
                 e0 + el;
#pragma unroll
      for (int r = 0; r < 4; ++r) {
        const float ca = ca_l[wr * 64 + i * 16 + quad * 4 + r];
        const float val = (ca != 0.0f) ? acc[i][j][r] * ca : NEGV * csum;
        p[(size_t)r * DD] = val * (1.0f / DD);
      }
    }
  }
}

extern "C" void kernel_launch(void* const* d_in, const int* in_sizes, int n_in,
                              void* d_out, int out_size, void* d_ws,
                              size_t ws_size, hipStream_t stream) {
  const float* Q = (const float*)d_in[0];
  const float* K = (const float*)d_in[1];
  const float* V = (const float*)d_in[2];
  const int* mask = (const int*)d_in[3];
  float* out = (float*)d_out;

  // Compact layout (49MB + 8KB; R7-verified).
  char* ws = (char*)d_ws;
  const size_t MB = (size_t)1024 * 1024;
  unsigned short* KT = (unsigned short*)(ws);              // bf16 chunked 16MB
  unsigned short* VT = (unsigned short*)(ws + 16 * MB);    // bf16 chunked 16MB
  unsigned short* part = (unsigned short*)(ws + 32 * MB);  // bf16 [16][B][D][D] 16MB
  unsigned short* s1b = (unsigned short*)(ws + 48 * MB);   // bf16 [B][D][D] 1MB
  float* colsum = (float*)(ws + 49 * MB);                  // f32 [B][D] 8KB

  const int iters = SS / (64 * SPLIT);  // K-chunks of 64 per p2 block

  prep_kernel<<<dim3(SS / 32, BB, 2), 256, 0, stream>>>(K, V, KT, VT);
  p2_kernel<<<dim3(4, SPLIT, BB), 256, 0, stream>>>(KT, VT, part, iters);
  reduce_kernel<<<dim3(BB * DD * DD / (8 * 256)), 256, 0, stream>>>(part, s1b,
                                                                    colsum);
  p3_kernel<<<dim3(2, SS / 128, BB), 256, 0, stream>>>(Q, mask, s1b, colsum,
                                                       out);
}

// Round 10
// 167.123 us; speedup vs baseline: 1.0211x; 1.0211x over previous
//
#include <hip/hip_runtime.h>

#define BB 8
#define SS 4096
#define DD 256
#define NEGV -1000000000.0f
#define NCH (SS / 32)   // 128 s-chunks of 32
#define SPLIT 16

typedef float f32x4 __attribute__((ext_vector_type(4)));
typedef short s16x8 __attribute__((ext_vector_type(8)));

// float -> bf16 round-to-nearest-even (inputs finite)
static __device__ __forceinline__ unsigned short f2bf(float x) {
  unsigned int u = __builtin_bit_cast(unsigned int, x);
  u += 0x7fffu + ((u >> 16) & 1u);
  return (unsigned short)(u >> 16);
}
static __device__ __forceinline__ float bf2f(unsigned short h) {
  return __builtin_bit_cast(float, (unsigned int)h << 16);
}

// async global->LDS, 16B per lane; LDS dest = wave-uniform base + lane*16
static __device__ __forceinline__ void gload_lds16(
    const unsigned short* __restrict__ g, unsigned short* l) {
  __builtin_amdgcn_global_load_lds(
      (const __attribute__((address_space(1))) void*)g,
      (__attribute__((address_space(3))) void*)l, 16, 0, 0);
}

// ---------------------------------------------------------------------------
// prep: K/V only (Q folded into p3). grid (S/32,B,2): z=0 -> KT (scaled
// 1/|k|^2), z=1 -> VT. Chunked transpose dst[((b*NCH+sc)*D+d)*32+s'].
// R7-verified; at its thrice-measured pattern ceiling. No inter-block reuse
// -> T1 swizzle does not apply here (catalog: null without reuse).
// ---------------------------------------------------------------------------
__global__ __launch_bounds__(256, 4) void prep_kernel(
    const float* __restrict__ K, const float* __restrict__ V,
    unsigned short* __restrict__ KT, unsigned short* __restrict__ VT) {
  __shared__ unsigned short tile[32 * 260];
  const int b = blockIdx.y;
  const int sc = blockIdx.x;
  const int s0 = sc * 32;
  const int tid = threadIdx.x;
  const int w = tid >> 6, l = tid & 63;
  const int isK = (blockIdx.z == 0);
  const float* __restrict__ src = isK ? K : V;
  unsigned short* __restrict__ dst = isK ? KT : VT;

  float4 reg[8];
  float ps[8];
#pragma unroll
  for (int it = 0; it < 8; ++it) {
    const int row = it * 4 + w;
    reg[it] = *(const float4*)(src + ((size_t)b * SS + s0 + row) * DD + l * 4);
  }
#pragma unroll
  for (int it = 0; it < 8; ++it)
    ps[it] = reg[it].x * reg[it].x + reg[it].y * reg[it].y +
             reg[it].z * reg[it].z + reg[it].w * reg[it].w;
  float scl[8];
  if (isK) {
#pragma unroll
    for (int off = 32; off; off >>= 1)
#pragma unroll
      for (int it = 0; it < 8; ++it) ps[it] += __shfl_xor(ps[it], off);
#pragma unroll
    for (int it = 0; it < 8; ++it) scl[it] = 1.0f / ps[it];
  } else {
#pragma unroll
    for (int it = 0; it < 8; ++it) scl[it] = 1.0f;
  }
#pragma unroll
  for (int it = 0; it < 8; ++it) {
    const int row = it * 4 + w;
    ushort4 o;
    o.x = f2bf(reg[it].x * scl[it]);
    o.y = f2bf(reg[it].y * scl[it]);
    o.z = f2bf(reg[it].z * scl[it]);
    o.w = f2bf(reg[it].w * scl[it]);
    *(ushort4*)(tile + row * 260 + l * 4) = o;
  }
  __syncthreads();
  const size_t gbase = ((size_t)(b * NCH + sc) * DD + tid) * 32;
#pragma unroll
  for (int c = 0; c < 4; ++c) {
    union { unsigned short h[8]; uint4 v; } u;
#pragma unroll
    for (int j = 0; j < 8; ++j) u.h[j] = tile[(c * 8 + j) * 260 + tid];
    *(uint4*)(dst + gbase + c * 8) = u.v;
  }
}

// ---------------------------------------------------------------------------
// p2: part[y][b][e][d] (bf16) = sum_{s in chunk y} VT[e][s]*KT[d][s].
// R10: T1 XCD-grouped decode -- the 4 tile-blocks (2d x 2e) of one
// (split,b) group land on ONE XCD (id&7), so the KT/VT s-chunks each group
// shares are fetched from HBM once and L2-hit 3x (grid fully co-resident at
// 2 blocks/CU, so sharing is temporal-guaranteed). Body = R9-verified.
// ---------------------------------------------------------------------------
__global__ __launch_bounds__(256) void p2_kernel(
    const unsigned short* __restrict__ KT, const unsigned short* __restrict__ VT,
    unsigned short* __restrict__ part, int iters) {
  __shared__ unsigned short vt_l[2][128 * 32];
  __shared__ unsigned short kt_l[2][128 * 32];
  // XCD-grouped decode: xcd = id&7; 4 consecutive same-XCD slots = one group.
  const int id = blockIdx.x;
  const int xcd = id & 7, slot = id >> 3;
  const int xx = slot & 3;
  const int G = xcd * 16 + (slot >> 2);  // 0..127 = (split,b) group
  const int yy = G & 15;                 // split chunk
  const int b = G >> 4;
  const int d0 = (xx & 1) * 128;
  const int e0 = (xx >> 1) * 128;
  const int tid = threadIdx.x;
  const int w = tid >> 6, l = tid & 63;
  const int wr = w & 1, wc = w >> 1;
  const int quad = l >> 4, mr = l & 15;

  f32x4 acc[4][4];
#pragma unroll
  for (int i = 0; i < 4; ++i)
#pragma unroll
    for (int j = 0; j < 4; ++j) acc[i][j] = (f32x4){0.f, 0.f, 0.f, 0.f};

  for (int ks = 0; ks < iters; ++ks) {
    const int c0 = (yy * iters + ks) * 2;  // 32-wide chunk index
#pragma unroll
    for (int h = 0; h < 2; ++h) {
      const size_t vch = ((size_t)(b * NCH + c0 + h) * DD + e0) * 32 + l * 8;
      const size_t kch = ((size_t)(b * NCH + c0 + h) * DD + d0) * 32 + l * 8;
#pragma unroll
      for (int g = 0; g < 2; ++g) {
        const int r0 = w * 32 + g * 16;
        gload_lds16(VT + vch + (size_t)r0 * 32, &vt_l[h][r0 * 32]);
        gload_lds16(KT + kch + (size_t)r0 * 32, &kt_l[h][r0 * 32]);
      }
    }
    __syncthreads();
#pragma unroll
    for (int kh = 0; kh < 2; ++kh) {
      s16x8 af[4], bfr[4];
#pragma unroll
      for (int i = 0; i < 4; ++i)
        af[i] = *(const s16x8*)(&vt_l[kh][(wr * 64 + i * 16 + mr) * 32 + quad * 8]);
#pragma unroll
      for (int j = 0; j < 4; ++j)
        bfr[j] = *(const s16x8*)(&kt_l[kh][(wc * 64 + j * 16 + mr) * 32 + quad * 8]);
#pragma unroll
      for (int i = 0; i < 4; ++i)
#pragma unroll
        for (int j = 0; j < 4; ++j)
          acc[i][j] = __builtin_amdgcn_mfma_f32_16x16x32_bf16(af[i], bfr[j],
                                                              acc[i][j], 0, 0, 0);
    }
    __syncthreads();
  }

  unsigned short* pb = part + ((size_t)yy * BB + b) * DD * DD;
#pragma unroll
  for (int i = 0; i < 4; ++i) {
    const int e = e0 + wr * 64 + i * 16 + quad * 4;
#pragma unroll
    for (int j = 0; j < 4; ++j) {
      const int d = d0 + wc * 64 + j * 16 + mr;
      unsigned short* p = pb + (size_t)e * DD + d;
#pragma unroll
      for (int r = 0; r < 4; ++r) p[(size_t)r * DD] = f2bf(acc[i][j][r]);
    }
  }
}

// ---------------------------------------------------------------------------
// reduce: s1b[b][e][d] = bf16(sum_p part[p][b][e][d]); colsum[b][e] = f32
// sum over d (p3's masked-row path). Shuffle reduce, no atomics. R7-verified.
// ---------------------------------------------------------------------------
__global__ __launch_bounds__(256) void reduce_kernel(
    const unsigned short* __restrict__ part, unsigned short* __restrict__ s1b,
    float* __restrict__ colsum) {
  const int tid = threadIdx.x;
  const size_t i8 = ((size_t)blockIdx.x * 256 + tid) * 8;
  float a[8];
#pragma unroll
  for (int j = 0; j < 8; ++j) a[j] = 0.f;
  for (int p = 0; p < SPLIT; ++p) {
    union { uint4 v; unsigned short h[8]; } u;
    u.v = *(const uint4*)(part + (size_t)p * (BB * DD * DD) + i8);
#pragma unroll
    for (int j = 0; j < 8; ++j) a[j] += bf2f(u.h[j]);
  }
  union { uint4 v; unsigned short h[8]; } o;
#pragma unroll
  for (int j = 0; j < 8; ++j) o.h[j] = f2bf(a[j]);
  *(uint4*)(s1b + i8) = o.v;
  float rp = (a[0] + a[1]) + (a[2] + a[3]) + ((a[4] + a[5]) + (a[6] + a[7]));
  rp += __shfl_xor(rp, 1);
  rp += __shfl_xor(rp, 2);
  rp += __shfl_xor(rp, 4);
  rp += __shfl_xor(rp, 8);
  rp += __shfl_xor(rp, 16);
  if ((tid & 31) == 0) {
    const int e = (int)((i8 >> 8) & 255);
    const int bb = (int)(i8 >> 16);
    colsum[bb * DD + e] = rp;
  }
}

// ---------------------------------------------------------------------------
// p3: out[b][s][e] = (1/D)*( mask[s] ? NEG*colsum[e]
//                                    : (1/|Q_s|^2) * sum_d Q[s][d]*s1b[e][d] )
// R10: T1 XCD-grouped decode -- the 2 e-tile blocks sharing one (s,b) Q-row
// panel land on ONE XCD, so the second block's Q reads L2-hit (per-k-step
// shared Q chunk 32KB x 32 groups = 1MB per XCD L2). Body = R9-verified
// (T14 double-buffer kept: neutral but harmless).
// ---------------------------------------------------------------------------
__global__ __launch_bounds__(256) void p3_kernel(
    const float* __restrict__ Q, const int* __restrict__ mask,
    const unsigned short* __restrict__ s1b, const float* __restrict__ colsum,
    float* __restrict__ out) {
  __shared__ unsigned short qs_l[2][2][128 * 32 + 16];
  __shared__ unsigned short s1_l[2][2][128 * 32];
  __shared__ float ps_l[128];
  __shared__ float ca_l[128];
  __shared__ float cs_l[128];
  // XCD-grouped decode: 2 consecutive same-XCD slots = both e-tiles of (s,b).
  const int id = blockIdx.x;
  const int xcd = id & 7, slot = id >> 3;
  const int e0 = (slot & 1) * 128;
  const int G = xcd * 32 + (slot >> 1);  // 0..255 = (s,b) group
  const int s0 = (G & 31) * 128;
  const int b = G >> 5;
  const int tid = threadIdx.x;
  const int w = tid >> 6, l = tid & 63;
  const int wr = w & 1, wc = w >> 1;
  const int quad = l >> 4, mr = l & 15;
  const int lr = l >> 2;
  const int lc = (l & 3) * 8;
  const int rg = tid >> 4;   // row group: rows rg, rg+16, ..., rg+112
  const int c4 = tid & 15;   // float4 column within the 64-d k-step

  if (tid < 128) cs_l[tid] = colsum[b * DD + e0 + tid];

  f32x4 acc[4][4];
#pragma unroll
  for (int i = 0; i < 4; ++i)
#pragma unroll
    for (int j = 0; j < 4; ++j) acc[i][j] = (f32x4){0.f, 0.f, 0.f, 0.f};
  float np[8];
#pragma unroll
  for (int u = 0; u < 8; ++u) np[u] = 0.f;

  auto stageS1 = [&](int buf, int ks) {
    const int dc = ks * 64;
#pragma unroll
    for (int h = 0; h < 2; ++h)
#pragma unroll
      for (int g = 0; g < 2; ++g) {
        const int r0 = w * 32 + g * 16;
        gload_lds16(s1b + ((size_t)b * DD + e0 + r0 + lr) * DD + dc + h * 32 + lc,
                    &s1_l[buf][h][r0 * 32]);
      }
  };
  auto loadQ = [&](int ks, float4* qv) {
    const int dc = ks * 64;
#pragma unroll
    for (int u = 0; u < 8; ++u) {
      const int row = rg + u * 16;
      qv[u] = *(const float4*)(Q + ((size_t)b * SS + s0 + row) * DD + dc + c4 * 4);
    }
  };
  auto writeQ = [&](int buf, const float4* qv) {
#pragma unroll
    for (int u = 0; u < 8; ++u) {
      np[u] += qv[u].x * qv[u].x + qv[u].y * qv[u].y + qv[u].z * qv[u].z +
               qv[u].w * qv[u].w;
      ushort4 o;
      o.x = f2bf(qv[u].x); o.y = f2bf(qv[u].y);
      o.z = f2bf(qv[u].z); o.w = f2bf(qv[u].w);
      *(ushort4*)&qs_l[buf][c4 >> 3][(rg + u * 16) * 32 + (c4 & 7) * 4] = o;
    }
  };

  // prologue: stage ks=0 (latency exposed once)
  float4 qvA[8], qvB[8];
  stageS1(0, 0);
  loadQ(0, qvA);
  writeQ(0, qvA);
  __syncthreads();

  for (int ks = 0; ks < 4; ++ks) {
    const int cur = ks & 1;
    if (ks < 3) {
      stageS1(cur ^ 1, ks + 1);  // DMA: latency hidden under MFMAs
      loadQ(ks + 1, qvB);        // reg loads: vmcnt wait lands in writeQ below
    }
#pragma unroll
    for (int kh = 0; kh < 2; ++kh) {
      s16x8 af[4], bfr[4];
#pragma unroll
      for (int i = 0; i < 4; ++i)
        af[i] = *(const s16x8*)(&qs_l[cur][kh][(wr * 64 + i * 16 + mr) * 32 + quad * 8]);
#pragma unroll
      for (int j = 0; j < 4; ++j)
        bfr[j] = *(const s16x8*)(&s1_l[cur][kh][(wc * 64 + j * 16 + mr) * 32 + quad * 8]);
#pragma unroll
      for (int i = 0; i < 4; ++i)
#pragma unroll
        for (int j = 0; j < 4; ++j)
          acc[i][j] = __builtin_amdgcn_mfma_f32_16x16x32_bf16(af[i], bfr[j],
                                                              acc[i][j], 0, 0, 0);
    }
    if (ks < 3) writeQ(cur ^ 1, qvB);  // consume Q regs after MFMA cluster
    __syncthreads();
  }

  // finalize row norms: reduce over the 16-thread group (c4 axis)
#pragma unroll
  for (int u = 0; u < 8; ++u) {
    np[u] += __shfl_xor(np[u], 1);
    np[u] += __shfl_xor(np[u], 2);
    np[u] += __shfl_xor(np[u], 4);
    np[u] += __shfl_xor(np[u], 8);
  }
  if (c4 == 0) {
#pragma unroll
    for (int u = 0; u < 8; ++u) ps_l[rg + u * 16] = np[u];
  }
  __syncthreads();
  if (tid < 128) {
    const int mk = mask[b * SS + s0 + tid];
    ca_l[tid] = mk ? 0.0f : (1.0f / ps_l[tid]);  // 0 == masked sentinel
  }
  __syncthreads();

#pragma unroll
  for (int i = 0; i < 4; ++i) {
#pragma unroll
    for (int j = 0; j < 4; ++j) {
      const int el = wc * 64 + j * 16 + mr;
      const float csum = cs_l[el];
      float* p = out + ((size_t)b * SS + s0 + wr * 64 + i * 16 + quad * 4) * DD +
                 e0 + el;
#pragma unroll
      for (int r = 0; r < 4; ++r) {
        const float ca = ca_l[wr * 64 + i * 16 + quad * 4 + r];
        const float val = (ca != 0.0f) ? acc[i][j][r] * ca : NEGV * csum;
        p[(size_t)r * DD] = val * (1.0f / DD);
      }
    }
  }
}

extern "C" void kernel_launch(void* const* d_in, const int* in_sizes, int n_in,
                              void* d_out, int out_size, void* d_ws,
                              size_t ws_size, hipStream_t stream) {
  const float* Q = (const float*)d_in[0];
  const float* K = (const float*)d_in[1];
  const float* V = (const float*)d_in[2];
  const int* mask = (const int*)d_in[3];
  float* out = (float*)d_out;

  // Compact layout (49MB + 8KB; R7-verified).
  char* ws = (char*)d_ws;
  const size_t MB = (size_t)1024 * 1024;
  unsigned short* KT = (unsigned short*)(ws);              // bf16 chunked 16MB
  unsigned short* VT = (unsigned short*)(ws + 16 * MB);    // bf16 chunked 16MB
  unsigned short* part = (unsigned short*)(ws + 32 * MB);  // bf16 [16][B][D][D] 16MB
  unsigned short* s1b = (unsigned short*)(ws + 48 * MB);   // bf16 [B][D][D] 1MB
  float* colsum = (float*)(ws + 49 * MB);                  // f32 [B][D] 8KB

  const int iters = SS / (64 * SPLIT);  // K-chunks of 64 per p2 block

  prep_kernel<<<dim3(SS / 32, BB, 2), 256, 0, stream>>>(K, V, KT, VT);
  p2_kernel<<<dim3(512), 256, 0, stream>>>(KT, VT, part, iters);
  reduce_kernel<<<dim3(BB * DD * DD / (8 * 256)), 256, 0, stream>>>(part, s1b,
                                                                    colsum);
  p3_kernel<<<dim3(512), 256, 0, stream>>>(Q, mask, s1b, colsum, out);
}